// Round 1
// baseline (714.840 us; speedup 1.0000x reference)
//
#include <hip/hip_runtime.h>
#include <hip/hip_bf16.h>

// Problem constants (GLA layer): D_MODEL=1024, D_K=D_V=64, H=16, B=4, T=2048
#define DM   1024
#define NH   16
#define TSEQ 2048
#define BBATCH 4
#define MM   (BBATCH*TSEQ)   // 8192 rows of x

typedef unsigned short USH;
typedef __attribute__((ext_vector_type(8))) short bf16x8;
typedef __attribute__((ext_vector_type(4))) float f32x4;

__device__ __forceinline__ USH f2bf(float f) {
  __hip_bfloat16 h = __float2bfloat16(f);
  return __builtin_bit_cast(USH, h);
}
__device__ __forceinline__ float bflo(unsigned u) { return __uint_as_float(u << 16); }
__device__ __forceinline__ float bfhi(unsigned u) { return __uint_as_float(u & 0xffff0000u); }

// async global->LDS, 16B per lane. LDS dst = wave-uniform base + lane*16.
__device__ __forceinline__ void load16_lds(const void* g, void* l) {
  __builtin_amdgcn_global_load_lds(
      (const __attribute__((address_space(1))) unsigned int*)g,
      (__attribute__((address_space(3))) unsigned int*)l, 16, 0, 0);
}

// ---------------- elementwise f32 -> bf16 (x) ----------------
__global__ void cvt_x(const float* __restrict__ x, USH* __restrict__ xb) {
  int i = (blockIdx.x * blockDim.x + threadIdx.x) * 4;
  float4 f = *(const float4*)(x + i);
  ushort4 u;
  u.x = f2bf(f.x); u.y = f2bf(f.y); u.z = f2bf(f.z); u.w = f2bf(f.w);
  *(ushort4*)(xb + i) = u;
}

// ------------- transpose+convert 1024x1024 f32 -> bf16 (B^T layout) -------------
// z<4: dst = WcatT + z*1M  (concat of Wq,Wk,Wv,Wg transposed);  z==4: dst = WoT
__global__ void trans_cvt(const float* __restrict__ w0, const float* __restrict__ w1,
                          const float* __restrict__ w2, const float* __restrict__ w3,
                          const float* __restrict__ w4,
                          USH* __restrict__ wcatT, USH* __restrict__ woT) {
  int z = blockIdx.z;
  const float* src = (z == 0) ? w0 : (z == 1) ? w1 : (z == 2) ? w2 : (z == 3) ? w3 : w4;
  USH* dst = (z < 4) ? (wcatT + (size_t)z * 1024 * 1024) : woT;
  __shared__ float tile[32][33];
  int x = blockIdx.x * 32 + threadIdx.x;   // col n of src
  int y = blockIdx.y * 32;                 // row k of src
  for (int j = threadIdx.y; j < 32; j += 8)
    tile[j][threadIdx.x] = src[(size_t)(y + j) * 1024 + x];
  __syncthreads();
  int x2 = blockIdx.y * 32 + threadIdx.x;  // k
  int y2 = blockIdx.x * 32;                // n
  for (int j = threadIdx.y; j < 32; j += 8)
    dst[(size_t)(y2 + j) * 1024 + x2] = f2bf(tile[threadIdx.x][j]);
}

// ---------------- MFMA GEMM: C(MxN) = A(MxK) * B^T(NxK), bf16 in, f32 acc ----------------
// 128x128 tile, BK=64, 256 threads (4 waves, 2x2 of 64x64), 16x16x32 bf16 MFMA.
// EPI=0: plain f32 store to c_out (row stride 1024).
// EPI=1: N=4096 fused QKVG epilogue: quarters -> q/k/v bf16, gate -> sigmoid fp32.
template <int EPI>
__global__ __launch_bounds__(256, 2) void gemm_bt(
    const USH* __restrict__ A, const USH* __restrict__ B, int K,
    USH* __restrict__ q_out, USH* __restrict__ k_out, USH* __restrict__ v_out,
    float* __restrict__ a_out, const float* __restrict__ bias,
    float* __restrict__ c_out) {
  __shared__ short As[128 * 64];
  __shared__ short Bs[128 * 64];
  const int tid = threadIdx.x;
  const int wave = tid >> 6;
  const int lane = tid & 63;
  const int bm = blockIdx.y, bn = blockIdx.x;
  const int wm = (wave >> 1) * 64;
  const int wn = (wave & 1) * 64;

  f32x4 acc[4][4];
#pragma unroll
  for (int i = 0; i < 4; i++)
#pragma unroll
    for (int j = 0; j < 4; j++) acc[i][j] = (f32x4){0.f, 0.f, 0.f, 0.f};

  const int srow = wave * 8 + (lane >> 3);  // row within 32-row staging group
  const int scol = (lane & 7) * 8;          // k offset (8 bf16 = 16B)

  for (int k0 = 0; k0 < K; k0 += 64) {
#pragma unroll
    for (int i = 0; i < 4; ++i) {
      int row = i * 32 + srow;
      const USH* ga = A + (size_t)(bm * 128 + row) * K + k0 + scol;
      const USH* gb = B + (size_t)(bn * 128 + row) * K + k0 + scol;
      int lofs = __builtin_amdgcn_readfirstlane((i * 32 + wave * 8) * 64);
      load16_lds(ga, (void*)(As + lofs));
      load16_lds(gb, (void*)(Bs + lofs));
    }
    __syncthreads();  // drains vmcnt -> staged data visible
#pragma unroll
    for (int ks = 0; ks < 64; ks += 32) {
      bf16x8 af[4], bf[4];
#pragma unroll
      for (int i = 0; i < 4; i++)
        af[i] = *(const bf16x8*)&As[(wm + i * 16 + (lane & 15)) * 64 + ks + (lane >> 4) * 8];
#pragma unroll
      for (int j = 0; j < 4; j++)
        bf[j] = *(const bf16x8*)&Bs[(wn + j * 16 + (lane & 15)) * 64 + ks + (lane >> 4) * 8];
#pragma unroll
      for (int i = 0; i < 4; i++)
#pragma unroll
        for (int j = 0; j < 4; j++)
          acc[i][j] = __builtin_amdgcn_mfma_f32_16x16x32_bf16(af[i], bf[j], acc[i][j], 0, 0, 0);
    }
    __syncthreads();
  }

  // epilogue. C/D layout: col = lane&15, row = (lane>>4)*4 + reg  [m89-verified]
  const int r0 = (lane >> 4) * 4;
  const int cc = lane & 15;
#pragma unroll
  for (int i = 0; i < 4; i++) {
#pragma unroll
    for (int j = 0; j < 4; j++) {
      int gn = bn * 128 + wn + j * 16 + cc;
#pragma unroll
      for (int r = 0; r < 4; r++) {
        int gm = bm * 128 + wm + i * 16 + r0 + r;
        float val = acc[i][j][r];
        if (EPI == 0) {
          c_out[(size_t)gm * 1024 + gn] = val;
        } else {
          int which = gn >> 10, cn = gn & 1023;  // uniform per 16-col tile
          size_t idx = (size_t)gm * 1024 + cn;
          if (which == 0)      q_out[idx] = f2bf(val);
          else if (which == 1) k_out[idx] = f2bf(val);
          else if (which == 2) v_out[idx] = f2bf(val);
          else {
            float s = 1.0f / (1.0f + __expf(-(val + bias[cn])));
            a_out[idx] = s;  // gate MUST stay fp32 (bf16 gate -> ~2% output error)
          }
        }
      }
    }
  }
}

// ---------------- fp32 sequential scan ----------------
// S[b,h,k,v] = a_t[k]*S + k_t[k]*v_t[v];  o_t[v] = sum_k q_t[k]*S[k,v]
// Grid: 256 WGs = 64 (b,h) x 4 v-splits of 16 cols. 256 thr: tid = v_local*16 + kg,
// thread owns S[kg*4 .. kg*4+3][v_local]; dot reduced over 16 lanes (same wave).
__global__ __launch_bounds__(256, 1) void gla_scan(
    const USH* __restrict__ qb, const USH* __restrict__ kb, const USH* __restrict__ vb,
    const float* __restrict__ af, USH* __restrict__ ob) {
  constexpr int CH = 16;
  constexpr int NC = TSEQ / CH;  // 128 chunks
  const int wg = blockIdx.x;
  const int bh = wg >> 2, vs = wg & 3;
  const size_t base = (size_t)(bh >> 4) * TSEQ * 1024 + (size_t)(bh & 15) * 64;
  const int tid = threadIdx.x;
  const int vl = tid >> 4, kg = tid & 15;

  __shared__ USH sq[2][CH][64];
  __shared__ USH sk[2][CH][64];
  __shared__ float sa[2][CH][64];
  __shared__ USH sv[2][CH][16];
  __shared__ USH so[CH][16];

  const int lt = tid >> 4;          // chunk-row this thread loads (q/k/a)
  const int lc = (tid & 15) * 4;    // 4 cols

  float S0 = 0.f, S1 = 0.f, S2 = 0.f, S3 = 0.f;
  uint2 rq, rk, rv;
  float4 ra;

  auto gload = [&](int c) {
    size_t r = base + (size_t)(c * CH + lt) * 1024 + lc;
    rq = *(const uint2*)(qb + r);
    rk = *(const uint2*)(kb + r);
    ra = *(const float4*)(af + r);
    if (tid < 64) {
      size_t rr = base + (size_t)(c * CH + (tid >> 2)) * 1024 + vs * 16 + (tid & 3) * 4;
      rv = *(const uint2*)(vb + rr);
    }
  };
  auto lstore = [&](int pb) {
    *(uint2*)&sq[pb][lt][lc] = rq;
    *(uint2*)&sk[pb][lt][lc] = rk;
    *(float4*)&sa[pb][lt][lc] = ra;
    if (tid < 64) *(uint2*)&sv[pb][tid >> 2][(tid & 3) * 4] = rv;
  };

  gload(0);
  lstore(0);
  __syncthreads();
  for (int c = 0; c < NC; ++c) {
    if (c + 1 < NC) gload(c + 1);
    const int pb = c & 1;
#pragma unroll
    for (int t = 0; t < CH; ++t) {
      float4 a4 = *(const float4*)&sa[pb][t][kg * 4];
      unsigned k2x = *(const unsigned*)&sk[pb][t][kg * 4];
      unsigned k2y = *(const unsigned*)&sk[pb][t][kg * 4 + 2];
      unsigned q2x = *(const unsigned*)&sq[pb][t][kg * 4];
      unsigned q2y = *(const unsigned*)&sq[pb][t][kg * 4 + 2];
      float vv = bflo(sv[pb][t][vl]);
      S0 = fmaf(a4.x, S0, bflo(k2x) * vv);
      S1 = fmaf(a4.y, S1, bfhi(k2x) * vv);
      S2 = fmaf(a4.z, S2, bflo(k2y) * vv);
      S3 = fmaf(a4.w, S3, bfhi(k2y) * vv);
      float p = bflo(q2x) * S0 + bfhi(q2x) * S1 + bflo(q2y) * S2 + bfhi(q2y) * S3;
      p += __shfl_xor(p, 1, 64);
      p += __shfl_xor(p, 2, 64);
      p += __shfl_xor(p, 4, 64);
      p += __shfl_xor(p, 8, 64);
      if (kg == 0) so[t][vl] = f2bf(p);
    }
    __syncthreads();
    ob[base + (size_t)(c * CH + (tid >> 4)) * 1024 + vs * 16 + (tid & 15)] = so[tid >> 4][tid & 15];
    if (c + 1 < NC) lstore((c + 1) & 1);
    __syncthreads();
  }
}

extern "C" void kernel_launch(void* const* d_in, const int* in_sizes, int n_in,
                              void* d_out, int out_size, void* d_ws, size_t ws_size,
                              hipStream_t stream) {
  const float* x  = (const float*)d_in[0];
  const float* Wq = (const float*)d_in[1];
  const float* Wk = (const float*)d_in[2];
  const float* Wv = (const float*)d_in[3];
  const float* Wg = (const float*)d_in[4];
  const float* bg = (const float*)d_in[5];
  const float* Wo = (const float*)d_in[6];
  float* out = (float*)d_out;

  // workspace layout (needs ~106 MiB)
  char* ws = (char*)d_ws;
  size_t off = 0;
  auto alloc = [&](size_t bytes) {
    char* p = ws + off;
    off += (bytes + 255) & ~(size_t)255;
    return p;
  };
  USH* xb    = (USH*)alloc((size_t)MM * DM * 2);        // 16 MiB (reused as ob)
  USH* WcatT = (USH*)alloc((size_t)4 * 1024 * 1024 * 2); // 8 MiB
  USH* WoT   = (USH*)alloc((size_t)1024 * 1024 * 2);     // 2 MiB
  USH* qb    = (USH*)alloc((size_t)MM * DM * 2);         // 16 MiB
  USH* kb    = (USH*)alloc((size_t)MM * DM * 2);         // 16 MiB
  USH* vb    = (USH*)alloc((size_t)MM * DM * 2);         // 16 MiB
  float* af  = (float*)alloc((size_t)MM * DM * 4);       // 32 MiB (fp32 gate!)
  USH* ob = xb;  // xb is dead after GEMM1; scan output aliases it

  cvt_x<<<(MM * DM) / 1024, 256, 0, stream>>>(x, xb);
  trans_cvt<<<dim3(32, 32, 5), dim3(32, 8), 0, stream>>>(Wq, Wk, Wv, Wg, Wo, WcatT, WoT);
  // fused QKV+gate GEMM: (8192x1024) x (1024x4096)
  gemm_bt<1><<<dim3(32, 64), 256, 0, stream>>>(xb, WcatT, 1024, qb, kb, vb, af, bg, nullptr);
  // sequential gated scan
  gla_scan<<<256, 256, 0, stream>>>(qb, kb, vb, af, ob);
  // output projection: (8192x1024) x (1024x1024) -> f32 d_out
  gemm_bt<0><<<dim3(8, 64), 256, 0, stream>>>(ob, WoT, 1024, nullptr, nullptr, nullptr,
                                              nullptr, nullptr, out);
}

// Round 2
// 418.223 us; speedup vs baseline: 1.7092x; 1.7092x over previous
//
#include <hip/hip_runtime.h>
#include <hip/hip_bf16.h>

// Problem constants (GLA layer): D_MODEL=1024, D_K=D_V=64, H=16, B=4, T=2048
#define DM   1024
#define NH   16
#define TSEQ 2048
#define BBATCH 4
#define MM   (BBATCH*TSEQ)   // 8192 rows of x
#define SL   256             // segment length (time split for scan parallelism)
#define NSEG 8               // TSEQ / SL

typedef unsigned short USH;
typedef __attribute__((ext_vector_type(8))) short bf16x8;
typedef __attribute__((ext_vector_type(4))) float f32x4;

__device__ __forceinline__ USH f2bf(float f) {
  __hip_bfloat16 h = __float2bfloat16(f);
  return __builtin_bit_cast(USH, h);
}
__device__ __forceinline__ float bflo(unsigned u) { return __uint_as_float(u << 16); }
__device__ __forceinline__ float bfhi(unsigned u) { return __uint_as_float(u & 0xffff0000u); }

// async global->LDS, 16B per lane. LDS dst = wave-uniform base + lane*16.
__device__ __forceinline__ void load16_lds(const void* g, void* l) {
  __builtin_amdgcn_global_load_lds(
      (const __attribute__((address_space(1))) unsigned int*)g,
      (__attribute__((address_space(3))) unsigned int*)l, 16, 0, 0);
}

// ---------------- elementwise f32 -> bf16 (x) ----------------
__global__ void cvt_x(const float* __restrict__ x, USH* __restrict__ xb) {
  int i = (blockIdx.x * blockDim.x + threadIdx.x) * 4;
  float4 f = *(const float4*)(x + i);
  ushort4 u;
  u.x = f2bf(f.x); u.y = f2bf(f.y); u.z = f2bf(f.z); u.w = f2bf(f.w);
  *(ushort4*)(xb + i) = u;
}

// ------------- transpose+convert 1024x1024 f32 -> bf16 (B^T layout) -------------
__global__ void trans_cvt(const float* __restrict__ w0, const float* __restrict__ w1,
                          const float* __restrict__ w2, const float* __restrict__ w3,
                          const float* __restrict__ w4,
                          USH* __restrict__ wcatT, USH* __restrict__ woT) {
  int z = blockIdx.z;
  const float* src = (z == 0) ? w0 : (z == 1) ? w1 : (z == 2) ? w2 : (z == 3) ? w3 : w4;
  USH* dst = (z < 4) ? (wcatT + (size_t)z * 1024 * 1024) : woT;
  __shared__ float tile[32][33];
  int x = blockIdx.x * 32 + threadIdx.x;
  int y = blockIdx.y * 32;
  for (int j = threadIdx.y; j < 32; j += 8)
    tile[j][threadIdx.x] = src[(size_t)(y + j) * 1024 + x];
  __syncthreads();
  int x2 = blockIdx.y * 32 + threadIdx.x;
  int y2 = blockIdx.x * 32;
  for (int j = threadIdx.y; j < 32; j += 8)
    dst[(size_t)(y2 + j) * 1024 + x2] = f2bf(tile[threadIdx.x][j]);
}

// ---------------- MFMA GEMM: C(MxN) = A(MxK) * B^T(NxK), bf16 in, f32 acc ----------------
template <int EPI>
__global__ __launch_bounds__(256, 2) void gemm_bt(
    const USH* __restrict__ A, const USH* __restrict__ B, int K,
    USH* __restrict__ q_out, USH* __restrict__ k_out, USH* __restrict__ v_out,
    float* __restrict__ a_out, const float* __restrict__ bias,
    float* __restrict__ c_out) {
  __shared__ short As[128 * 64];
  __shared__ short Bs[128 * 64];
  const int tid = threadIdx.x;
  const int wave = tid >> 6;
  const int lane = tid & 63;
  const int bm = blockIdx.y, bn = blockIdx.x;
  const int wm = (wave >> 1) * 64;
  const int wn = (wave & 1) * 64;

  f32x4 acc[4][4];
#pragma unroll
  for (int i = 0; i < 4; i++)
#pragma unroll
    for (int j = 0; j < 4; j++) acc[i][j] = (f32x4){0.f, 0.f, 0.f, 0.f};

  const int srow = wave * 8 + (lane >> 3);
  const int scol = (lane & 7) * 8;

  for (int k0 = 0; k0 < K; k0 += 64) {
#pragma unroll
    for (int i = 0; i < 4; ++i) {
      int row = i * 32 + srow;
      const USH* ga = A + (size_t)(bm * 128 + row) * K + k0 + scol;
      const USH* gb = B + (size_t)(bn * 128 + row) * K + k0 + scol;
      int lofs = __builtin_amdgcn_readfirstlane((i * 32 + wave * 8) * 64);
      load16_lds(ga, (void*)(As + lofs));
      load16_lds(gb, (void*)(Bs + lofs));
    }
    __syncthreads();
#pragma unroll
    for (int ks = 0; ks < 64; ks += 32) {
      bf16x8 af[4], bf[4];
#pragma unroll
      for (int i = 0; i < 4; i++)
        af[i] = *(const bf16x8*)&As[(wm + i * 16 + (lane & 15)) * 64 + ks + (lane >> 4) * 8];
#pragma unroll
      for (int j = 0; j < 4; j++)
        bf[j] = *(const bf16x8*)&Bs[(wn + j * 16 + (lane & 15)) * 64 + ks + (lane >> 4) * 8];
#pragma unroll
      for (int i = 0; i < 4; i++)
#pragma unroll
        for (int j = 0; j < 4; j++)
          acc[i][j] = __builtin_amdgcn_mfma_f32_16x16x32_bf16(af[i], bf[j], acc[i][j], 0, 0, 0);
    }
    __syncthreads();
  }

  const int r0 = (lane >> 4) * 4;
  const int cc = lane & 15;
#pragma unroll
  for (int i = 0; i < 4; i++) {
#pragma unroll
    for (int j = 0; j < 4; j++) {
      int gn = bn * 128 + wn + j * 16 + cc;
#pragma unroll
      for (int r = 0; r < 4; r++) {
        int gm = bm * 128 + wm + i * 16 + r0 + r;
        float val = acc[i][j][r];
        if (EPI == 0) {
          c_out[(size_t)gm * 1024 + gn] = val;
        } else {
          int which = gn >> 10, cn = gn & 1023;
          size_t idx = (size_t)gm * 1024 + cn;
          if (which == 0)      q_out[idx] = f2bf(val);
          else if (which == 1) k_out[idx] = f2bf(val);
          else if (which == 2) v_out[idx] = f2bf(val);
          else {
            float s = 1.0f / (1.0f + __expf(-(val + bias[cn])));
            a_out[idx] = s;  // gate MUST stay fp32
          }
        }
      }
    }
  }
}

// ---------------- Pass 1: segmented local scan ----------------
// Grid: 512 WGs = 64 (b,h) x 8 segments. 1024 threads: tid = vq*256 + vl*16 + kg.
// Thread owns S_local[kg*4..+3][vq*16+vl]. Also (lanes tid<16) maintains cumprod A_t
// and overwrites qb with q~ = q*A (bf16, in-place — WG owns its row range).
// Outputs: o_local -> ob (bf16), segment end state -> SB, segment decay -> Dseg.
__global__ __launch_bounds__(1024, 8) void gla_scan_seg(
    USH* __restrict__ qb, const USH* __restrict__ kb, const USH* __restrict__ vb,
    const float* __restrict__ af, USH* __restrict__ ob,
    float* __restrict__ SB, float* __restrict__ Dseg) {
  constexpr int CH = 16;
  constexpr int NC = SL / CH;  // 16 chunks per segment
  const int bh = blockIdx.x >> 3, seg = blockIdx.x & 7;
  const size_t base = (size_t)(bh >> 4) * TSEQ * 1024 + (size_t)(bh & 15) * 64;
  const int trow0 = seg * SL;
  const int tid = threadIdx.x;
  const int vq = tid >> 8, vl = (tid >> 4) & 15, kg = tid & 15;
  const int v = vq * 16 + vl;

  __shared__ USH sq[2][CH][64];
  __shared__ USH sk[2][CH][64];
  __shared__ float sa[2][CH][64];
  __shared__ USH sv[2][CH][64];
  __shared__ USH so[CH][64];

  const int lg = tid >> 8;         // loader role: 0:q 1:k 2:a 3:v
  const int li = tid & 255;
  const int lrow = li >> 4, lcol = (li & 15) * 4;

  float S0 = 0.f, S1 = 0.f, S2 = 0.f, S3 = 0.f;
  float P0 = 1.f, P1 = 1.f, P2 = 1.f, P3 = 1.f;
  uint2 r2;
  float4 r4;

  auto gload = [&](int c) {
    size_t r = base + (size_t)(trow0 + c * CH + lrow) * 1024 + lcol;
    if (lg == 0)      r2 = *(const uint2*)(qb + r);
    else if (lg == 1) r2 = *(const uint2*)(kb + r);
    else if (lg == 2) r4 = *(const float4*)(af + r);
    else              r2 = *(const uint2*)(vb + r);
  };
  auto lstore = [&](int pb) {
    if (lg == 0)      *(uint2*)&sq[pb][lrow][lcol] = r2;
    else if (lg == 1) *(uint2*)&sk[pb][lrow][lcol] = r2;
    else if (lg == 2) *(float4*)&sa[pb][lrow][lcol] = r4;
    else              *(uint2*)&sv[pb][lrow][lcol] = r2;
  };

  gload(0);
  lstore(0);
  __syncthreads();
  for (int c = 0; c < NC; ++c) {
    if (c + 1 < NC) gload(c + 1);
    const int pb = c & 1;
#pragma unroll
    for (int t = 0; t < CH; ++t) {
      float4 a4 = *(const float4*)&sa[pb][t][kg * 4];
      unsigned k2x = *(const unsigned*)&sk[pb][t][kg * 4];
      unsigned k2y = *(const unsigned*)&sk[pb][t][kg * 4 + 2];
      unsigned q2x = *(const unsigned*)&sq[pb][t][kg * 4];
      unsigned q2y = *(const unsigned*)&sq[pb][t][kg * 4 + 2];
      float vv = bflo(sv[pb][t][v]);
      S0 = fmaf(a4.x, S0, bflo(k2x) * vv);
      S1 = fmaf(a4.y, S1, bfhi(k2x) * vv);
      S2 = fmaf(a4.z, S2, bflo(k2y) * vv);
      S3 = fmaf(a4.w, S3, bfhi(k2y) * vv);
      float p = bflo(q2x) * S0 + bfhi(q2x) * S1 + bflo(q2y) * S2 + bfhi(q2y) * S3;
      p += __shfl_xor(p, 1, 64);
      p += __shfl_xor(p, 2, 64);
      p += __shfl_xor(p, 4, 64);
      p += __shfl_xor(p, 8, 64);
      if (kg == 0) so[t][v] = f2bf(p);
      if (tid < 16) {  // cumprod + q~ in-place writeback (kg = tid here)
        P0 *= a4.x; P1 *= a4.y; P2 *= a4.z; P3 *= a4.w;
        ushort4 qt;
        qt.x = f2bf(bflo(q2x) * P0);
        qt.y = f2bf(bfhi(q2x) * P1);
        qt.z = f2bf(bflo(q2y) * P2);
        qt.w = f2bf(bfhi(q2y) * P3);
        *(ushort4*)(qb + base + (size_t)(trow0 + c * CH + t) * 1024 + kg * 4) = qt;
      }
    }
    __syncthreads();
    ob[base + (size_t)(trow0 + c * CH + (tid >> 6)) * 1024 + (tid & 63)] = so[tid >> 6][tid & 63];
    if (c + 1 < NC) lstore((c + 1) & 1);
    __syncthreads();
  }
  // segment-local end state S_loc -> SB[bh][seg][k][v]; decay D -> Dseg
  float* sl = SB + ((size_t)bh * 8 + seg) * 4096;
  sl[(kg * 4 + 0) * 64 + v] = S0;
  sl[(kg * 4 + 1) * 64 + v] = S1;
  sl[(kg * 4 + 2) * 64 + v] = S2;
  sl[(kg * 4 + 3) * 64 + v] = S3;
  if (tid < 16) {
    float4 d4 = {P0, P1, P2, P3};
    *(float4*)(Dseg + ((size_t)bh * 8 + seg) * 64 + kg * 4) = d4;
  }
}

// ---------------- Pass 2: stitch segment start states (in-place SB) ----------------
// SB[bh][s] on entry = S_loc[s]; on exit = S_start[s]. 64 WGs x 256 threads.
__global__ __launch_bounds__(256, 1) void gla_stitch(float* __restrict__ SB,
                                                     const float* __restrict__ Dseg) {
  const int bh = blockIdx.x;
  const int tid = threadIdx.x;
  const int k = tid >> 2, vg = (tid & 3) * 16;
  float s[16];
#pragma unroll
  for (int i = 0; i < 16; i++) s[i] = 0.f;
  for (int sg = 0; sg < NSEG; ++sg) {
    float* p = SB + ((size_t)bh * 8 + sg) * 4096 + (size_t)k * 64 + vg;
    float4 l0 = *(float4*)(p + 0), l1 = *(float4*)(p + 4);
    float4 l2 = *(float4*)(p + 8), l3 = *(float4*)(p + 12);
    float D = Dseg[((size_t)bh * 8 + sg) * 64 + k];
    *(float4*)(p + 0)  = (float4){s[0], s[1], s[2], s[3]};
    *(float4*)(p + 4)  = (float4){s[4], s[5], s[6], s[7]};
    *(float4*)(p + 8)  = (float4){s[8], s[9], s[10], s[11]};
    *(float4*)(p + 12) = (float4){s[12], s[13], s[14], s[15]};
    s[0] = fmaf(D, s[0], l0.x);  s[1] = fmaf(D, s[1], l0.y);
    s[2] = fmaf(D, s[2], l0.z);  s[3] = fmaf(D, s[3], l0.w);
    s[4] = fmaf(D, s[4], l1.x);  s[5] = fmaf(D, s[5], l1.y);
    s[6] = fmaf(D, s[6], l1.z);  s[7] = fmaf(D, s[7], l1.w);
    s[8] = fmaf(D, s[8], l2.x);  s[9] = fmaf(D, s[9], l2.y);
    s[10] = fmaf(D, s[10], l2.z); s[11] = fmaf(D, s[11], l2.w);
    s[12] = fmaf(D, s[12], l3.x); s[13] = fmaf(D, s[13], l3.y);
    s[14] = fmaf(D, s[14], l3.z); s[15] = fmaf(D, s[15], l3.w);
  }
}

// ---------------- Pass 3: o += q~ @ S_start, segments 1..7 ----------------
// Grid: (4 rowblocks of 64, 7 segs, 64 bh) x 256 threads.
__global__ __launch_bounds__(256, 4) void gla_corr(
    const USH* __restrict__ qtb, const float* __restrict__ SB, USH* __restrict__ ob) {
  const int bh = blockIdx.z, seg = blockIdx.y + 1, rb = blockIdx.x;
  const size_t base = (size_t)(bh >> 4) * TSEQ * 1024 + (size_t)(bh & 15) * 64;
  const int trow0 = seg * SL + rb * 64;
  const int tid = threadIdx.x;
  __shared__ float ss[64 * 64];    // S_start[k][v]
  __shared__ USH qs[64][72];       // q~ rows, +8 pad kills stride-128B bank conflict
  const float* sp = SB + ((size_t)bh * 8 + seg) * 4096;
  for (int i = tid; i < 1024; i += 256)
    *((float4*)ss + i) = *((const float4*)sp + i);
#pragma unroll
  for (int j = 0; j < 4; ++j) {
    int i = tid + 256 * j;
    int row = i >> 4, cg = (i & 15) * 4;
    *(uint2*)&qs[row][cg] = *(const uint2*)(qtb + base + (size_t)(trow0 + row) * 1024 + cg);
  }
  __syncthreads();
  const int row = tid >> 2, vg = (tid & 3) * 16;
  float acc[16];
#pragma unroll
  for (int i = 0; i < 16; i++) acc[i] = 0.f;
  for (int k0 = 0; k0 < 64; k0 += 8) {
    uint4 qv = *(const uint4*)&qs[row][k0];  // 8 bf16
    float qf[8];
    qf[0] = bflo(qv.x); qf[1] = bfhi(qv.x);
    qf[2] = bflo(qv.y); qf[3] = bfhi(qv.y);
    qf[4] = bflo(qv.z); qf[5] = bfhi(qv.z);
    qf[6] = bflo(qv.w); qf[7] = bfhi(qv.w);
#pragma unroll
    for (int j = 0; j < 8; ++j) {
      const float* sr = &ss[(k0 + j) * 64 + vg];
      float4 s0 = *(const float4*)(sr + 0), s1 = *(const float4*)(sr + 4);
      float4 s2 = *(const float4*)(sr + 8), s3 = *(const float4*)(sr + 12);
      acc[0] = fmaf(qf[j], s0.x, acc[0]);   acc[1] = fmaf(qf[j], s0.y, acc[1]);
      acc[2] = fmaf(qf[j], s0.z, acc[2]);   acc[3] = fmaf(qf[j], s0.w, acc[3]);
      acc[4] = fmaf(qf[j], s1.x, acc[4]);   acc[5] = fmaf(qf[j], s1.y, acc[5]);
      acc[6] = fmaf(qf[j], s1.z, acc[6]);   acc[7] = fmaf(qf[j], s1.w, acc[7]);
      acc[8] = fmaf(qf[j], s2.x, acc[8]);   acc[9] = fmaf(qf[j], s2.y, acc[9]);
      acc[10] = fmaf(qf[j], s2.z, acc[10]); acc[11] = fmaf(qf[j], s2.w, acc[11]);
      acc[12] = fmaf(qf[j], s3.x, acc[12]); acc[13] = fmaf(qf[j], s3.y, acc[13]);
      acc[14] = fmaf(qf[j], s3.z, acc[14]); acc[15] = fmaf(qf[j], s3.w, acc[15]);
    }
  }
  USH* op = ob + base + (size_t)(trow0 + row) * 1024 + vg;
#pragma unroll
  for (int g = 0; g < 4; ++g) {
    ushort4 o4 = *(ushort4*)(op + g * 4);
    o4.x = f2bf(bflo((unsigned)o4.x) + acc[g * 4 + 0]);
    o4.y = f2bf(bflo((unsigned)o4.y) + acc[g * 4 + 1]);
    o4.z = f2bf(bflo((unsigned)o4.z) + acc[g * 4 + 2]);
    o4.w = f2bf(bflo((unsigned)o4.w) + acc[g * 4 + 3]);
    *(ushort4*)(op + g * 4) = o4;
  }
}

extern "C" void kernel_launch(void* const* d_in, const int* in_sizes, int n_in,
                              void* d_out, int out_size, void* d_ws, size_t ws_size,
                              hipStream_t stream) {
  const float* x  = (const float*)d_in[0];
  const float* Wq = (const float*)d_in[1];
  const float* Wk = (const float*)d_in[2];
  const float* Wv = (const float*)d_in[3];
  const float* Wg = (const float*)d_in[4];
  const float* bg = (const float*)d_in[5];
  const float* Wo = (const float*)d_in[6];
  float* out = (float*)d_out;

  // workspace layout (~114 MiB)
  char* ws = (char*)d_ws;
  size_t off = 0;
  auto alloc = [&](size_t bytes) {
    char* p = ws + off;
    off += (bytes + 255) & ~(size_t)255;
    return p;
  };
  USH* xb    = (USH*)alloc((size_t)MM * DM * 2);         // 16 MiB (reused as ob)
  USH* WcatT = (USH*)alloc((size_t)4 * 1024 * 1024 * 2); // 8 MiB
  USH* WoT   = (USH*)alloc((size_t)1024 * 1024 * 2);     // 2 MiB
  USH* qb    = (USH*)alloc((size_t)MM * DM * 2);         // 16 MiB
  USH* kb    = (USH*)alloc((size_t)MM * DM * 2);         // 16 MiB
  USH* vb    = (USH*)alloc((size_t)MM * DM * 2);         // 16 MiB
  float* af  = (float*)alloc((size_t)MM * DM * 4);       // 32 MiB (fp32 gate)
  float* SB  = (float*)alloc((size_t)64 * 8 * 64 * 64 * 4); // 8 MiB  S_loc -> S_start
  float* Dseg = (float*)alloc((size_t)64 * 8 * 64 * 4);     // 128 KiB segment decay
  USH* ob = xb;  // xb dead after GEMM1

  cvt_x<<<(MM * DM) / 1024, 256, 0, stream>>>(x, xb);
  trans_cvt<<<dim3(32, 32, 5), dim3(32, 8), 0, stream>>>(Wq, Wk, Wv, Wg, Wo, WcatT, WoT);
  // fused QKV+gate GEMM: (8192x1024) x (1024x4096)
  gemm_bt<1><<<dim3(32, 64), 256, 0, stream>>>(xb, WcatT, 1024, qb, kb, vb, af, bg, nullptr);
  // segmented scan: local scans (also writes q~ over qb)
  gla_scan_seg<<<512, 1024, 0, stream>>>(qb, kb, vb, af, ob, SB, Dseg);
  // stitch segment start states (in-place in SB)
  gla_stitch<<<64, 256, 0, stream>>>(SB, Dseg);
  // cross-segment correction
  gla_corr<<<dim3(4, 7, 64), 256, 0, stream>>>(qb, SB, ob);
  // output projection: (8192x1024) x (1024x1024) -> f32 d_out
  gemm_bt<0><<<dim3(8, 64), 256, 0, stream>>>(ob, WoT, 1024, nullptr, nullptr, nullptr,
                                              nullptr, nullptr, out);
}

// Round 3
// 295.444 us; speedup vs baseline: 2.4195x; 1.4156x over previous
//
#include <hip/hip_runtime.h>
#include <hip/hip_bf16.h>

// Problem constants (GLA layer): D_MODEL=1024, D_K=D_V=64, H=16, B=4, T=2048
#define DM   1024
#define NH   16
#define TSEQ 2048
#define BBATCH 4
#define MM   (BBATCH*TSEQ)   // 8192 rows of x

typedef unsigned short USH;
typedef __attribute__((ext_vector_type(8))) short bf16x8;
typedef __attribute__((ext_vector_type(4))) float f32x4;

__device__ __forceinline__ USH f2bf(float f) {
  __hip_bfloat16 h = __float2bfloat16(f);
  return __builtin_bit_cast(USH, h);
}
__device__ __forceinline__ float bflo(unsigned u) { return __uint_as_float(u << 16); }
__device__ __forceinline__ float bfhi(unsigned u) { return __uint_as_float(u & 0xffff0000u); }

// async global->LDS, 16B per lane. LDS dst = wave-uniform base + lane*16.
__device__ __forceinline__ void load16_lds(const void* g, void* l) {
  __builtin_amdgcn_global_load_lds(
      (const __attribute__((address_space(1))) unsigned int*)g,
      (__attribute__((address_space(3))) unsigned int*)l, 16, 0, 0);
}

// ---------------- elementwise f32 -> bf16 (x) ----------------
__global__ void cvt_x(const float* __restrict__ x, USH* __restrict__ xb) {
  int i = (blockIdx.x * blockDim.x + threadIdx.x) * 4;
  float4 f = *(const float4*)(x + i);
  ushort4 u;
  u.x = f2bf(f.x); u.y = f2bf(f.y); u.z = f2bf(f.z); u.w = f2bf(f.w);
  *(ushort4*)(xb + i) = u;
}

// ------------- transpose+convert 1024x1024 f32 -> bf16 (B^T layout) -------------
__global__ void trans_cvt(const float* __restrict__ w0, const float* __restrict__ w1,
                          const float* __restrict__ w2, const float* __restrict__ w3,
                          const float* __restrict__ w4,
                          USH* __restrict__ wcatT, USH* __restrict__ woT) {
  int z = blockIdx.z;
  const float* src = (z == 0) ? w0 : (z == 1) ? w1 : (z == 2) ? w2 : (z == 3) ? w3 : w4;
  USH* dst = (z < 4) ? (wcatT + (size_t)z * 1024 * 1024) : woT;
  __shared__ float tile[32][33];
  int x = blockIdx.x * 32 + threadIdx.x;
  int y = blockIdx.y * 32;
  for (int j = threadIdx.y; j < 32; j += 8)
    tile[j][threadIdx.x] = src[(size_t)(y + j) * 1024 + x];
  __syncthreads();
  int x2 = blockIdx.y * 32 + threadIdx.x;
  int y2 = blockIdx.x * 32;
  for (int j = threadIdx.y; j < 32; j += 8)
    dst[(size_t)(y2 + j) * 1024 + x2] = f2bf(tile[threadIdx.x][j]);
}

// ---------------- MFMA GEMM: C(MxN) = A(MxK) * B^T(NxK), bf16 in, f32 acc ----------------
// EPI=1: N=4096 fused QKVG epilogue: q/k/v bf16, gate -> sigmoid as u16 fixed-point.
template <int EPI>
__global__ __launch_bounds__(256, 2) void gemm_bt(
    const USH* __restrict__ A, const USH* __restrict__ B, int K,
    USH* __restrict__ q_out, USH* __restrict__ k_out, USH* __restrict__ v_out,
    USH* __restrict__ a_out, const float* __restrict__ bias,
    float* __restrict__ c_out) {
  __shared__ short As[128 * 64];
  __shared__ short Bs[128 * 64];
  const int tid = threadIdx.x;
  const int wave = tid >> 6;
  const int lane = tid & 63;
  const int bm = blockIdx.y, bn = blockIdx.x;
  const int wm = (wave >> 1) * 64;
  const int wn = (wave & 1) * 64;

  f32x4 acc[4][4];
#pragma unroll
  for (int i = 0; i < 4; i++)
#pragma unroll
    for (int j = 0; j < 4; j++) acc[i][j] = (f32x4){0.f, 0.f, 0.f, 0.f};

  const int srow = wave * 8 + (lane >> 3);
  const int scol = (lane & 7) * 8;

  for (int k0 = 0; k0 < K; k0 += 64) {
#pragma unroll
    for (int i = 0; i < 4; ++i) {
      int row = i * 32 + srow;
      const USH* ga = A + (size_t)(bm * 128 + row) * K + k0 + scol;
      const USH* gb = B + (size_t)(bn * 128 + row) * K + k0 + scol;
      int lofs = __builtin_amdgcn_readfirstlane((i * 32 + wave * 8) * 64);
      load16_lds(ga, (void*)(As + lofs));
      load16_lds(gb, (void*)(Bs + lofs));
    }
    __syncthreads();
#pragma unroll
    for (int ks = 0; ks < 64; ks += 32) {
      bf16x8 af[4], bf[4];
#pragma unroll
      for (int i = 0; i < 4; i++)
        af[i] = *(const bf16x8*)&As[(wm + i * 16 + (lane & 15)) * 64 + ks + (lane >> 4) * 8];
#pragma unroll
      for (int j = 0; j < 4; j++)
        bf[j] = *(const bf16x8*)&Bs[(wn + j * 16 + (lane & 15)) * 64 + ks + (lane >> 4) * 8];
#pragma unroll
      for (int i = 0; i < 4; i++)
#pragma unroll
        for (int j = 0; j < 4; j++)
          acc[i][j] = __builtin_amdgcn_mfma_f32_16x16x32_bf16(af[i], bf[j], acc[i][j], 0, 0, 0);
    }
    __syncthreads();
  }

  const int r0 = (lane >> 4) * 4;
  const int cc = lane & 15;
#pragma unroll
  for (int i = 0; i < 4; i++) {
#pragma unroll
    for (int j = 0; j < 4; j++) {
      int gn = bn * 128 + wn + j * 16 + cc;
#pragma unroll
      for (int r = 0; r < 4; r++) {
        int gm = bm * 128 + wm + i * 16 + r0 + r;
        float val = acc[i][j][r];
        if (EPI == 0) {
          c_out[(size_t)gm * 1024 + gn] = val;
        } else {
          int which = gn >> 10, cn = gn & 1023;
          size_t idx = (size_t)gm * 1024 + cn;
          if (which == 0)      q_out[idx] = f2bf(val);
          else if (which == 1) k_out[idx] = f2bf(val);
          else if (which == 2) v_out[idx] = f2bf(val);
          else {
            float s = 1.0f / (1.0f + __expf(-(val + bias[cn])));
            a_out[idx] = (USH)(s * 65535.0f + 0.5f);  // u16 gate: rel err ~8e-6 (bf16 would be 1e-3)
          }
        }
      }
    }
  }
}

// ---------------- Pass A: per-chunk MFMA scan (C=64) ----------------
// Grid 2048 = 64 bh x 32 chunks, 256 threads (4 waves).
// P = (Q*A) @ (K/A)^T masked causal; O_intra = P@V; S_chunk = Khat^T@V; Dc = A[63].
// Writes q~ in-place to qb (bf16) for pass C.
__global__ __launch_bounds__(256, 3) void gla_chunk(
    USH* __restrict__ qb, const USH* __restrict__ kb, const USH* __restrict__ vb,
    const USH* __restrict__ au, USH* __restrict__ ob,
    float* __restrict__ SB, float* __restrict__ Dc) {
  const int bh = blockIdx.x >> 5, ch = blockIdx.x & 31;
  const size_t base = (size_t)(bh >> 4) * TSEQ * 1024 + (size_t)(bh & 15) * 64;
  const int row0 = ch * 64;
  const int tid = threadIdx.x, wv = tid >> 6, ln = tid & 63;

  __shared__ __align__(16) char smem[54528];
  USH* Qs  = (USH*)smem;             // [64][72] bf16 q~
  USH* Ks  = (USH*)(smem + 9216);    // [64][72] bf16 k~ (rows s)
  USH* Kht = (USH*)(smem + 18432);   // [64][72] bf16 k^ transposed (rows k)
  USH* Vt  = (USH*)(smem + 27648);   // [64][72] bf16 V transposed (rows v)
  float* psum = (float*)(smem + 27648);  // aliases Vt head; dead before Vt written
  USH* Ps  = (USH*)(smem + 36864);   // [64][72] masked P, bf16 (aliases Ag)
  USH* so  = (USH*)(smem + 46080);   // [64][66] O_intra bf16 (aliases Ag tail)
  float* Ag = (float*)(smem + 36864); // [64][65] fp32 cumprod; dead before Ps/so

  // ---- phase 1: per-column cumulative product of gates (fp32) ----
  {
    const int c1 = tid & 63, sg = tid >> 6;
    float lp[16], p = 1.f;
#pragma unroll
    for (int r = 0; r < 16; ++r) {
      float a = (float)au[base + (size_t)(row0 + sg * 16 + r) * 1024 + c1] * (1.f / 65535.f);
      p *= a;
      lp[r] = p;
    }
    psum[sg * 64 + c1] = p;
    __syncthreads();
    float pre = 1.f;
    for (int s2 = 0; s2 < sg; ++s2) pre *= psum[s2 * 64 + c1];
#pragma unroll
    for (int r = 0; r < 16; ++r) Ag[(sg * 16 + r) * 65 + c1] = pre * lp[r];
  }
  __syncthreads();
  if (tid < 64) Dc[((size_t)bh * 32 + ch) * 64 + tid] = Ag[63 * 65 + tid];

  // ---- phase 2: build q~, k~, k^T, V^T in LDS; write q~ back to qb ----
  {
    const int rr = tid >> 4, cg = (tid & 15) * 4;
    float AC[4];
#pragma unroll
    for (int i = 0; i < 4; i++) AC[i] = Ag[63 * 65 + cg + i];
#pragma unroll
    for (int j = 0; j < 4; ++j) {
      int row = rr + j * 16;
      size_t g = base + (size_t)(row0 + row) * 1024 + cg;
      uint2 qv = *(const uint2*)(qb + g);
      uint2 kv = *(const uint2*)(kb + g);
      uint2 vv = *(const uint2*)(vb + g);
      float A0 = Ag[row * 65 + cg], A1 = Ag[row * 65 + cg + 1];
      float A2 = Ag[row * 65 + cg + 2], A3 = Ag[row * 65 + cg + 3];
      ushort4 qt;
      qt.x = f2bf(bflo(qv.x) * A0); qt.y = f2bf(bfhi(qv.x) * A1);
      qt.z = f2bf(bflo(qv.y) * A2); qt.w = f2bf(bfhi(qv.y) * A3);
      *(ushort4*)&Qs[row * 72 + cg] = qt;
      *(ushort4*)(qb + g) = qt;  // for pass C
      float R0 = 1.f / A0, R1 = 1.f / A1, R2 = 1.f / A2, R3 = 1.f / A3;
      float kt0 = bflo(kv.x) * R0, kt1 = bfhi(kv.x) * R1;
      float kt2 = bflo(kv.y) * R2, kt3 = bfhi(kv.y) * R3;
      ushort4 kt;
      kt.x = f2bf(kt0); kt.y = f2bf(kt1); kt.z = f2bf(kt2); kt.w = f2bf(kt3);
      *(ushort4*)&Ks[row * 72 + cg] = kt;
      Kht[(cg + 0) * 72 + row] = f2bf(kt0 * AC[0]);
      Kht[(cg + 1) * 72 + row] = f2bf(kt1 * AC[1]);
      Kht[(cg + 2) * 72 + row] = f2bf(kt2 * AC[2]);
      Kht[(cg + 3) * 72 + row] = f2bf(kt3 * AC[3]);
      Vt[(cg + 0) * 72 + row] = (USH)(vv.x & 0xffff);
      Vt[(cg + 1) * 72 + row] = (USH)(vv.x >> 16);
      Vt[(cg + 2) * 72 + row] = (USH)(vv.y & 0xffff);
      Vt[(cg + 3) * 72 + row] = (USH)(vv.y >> 16);
    }
  }
  __syncthreads();

  const int q4 = (ln >> 4) * 4, cc = ln & 15, m16 = ln & 15;

  // ---- MFMA1: P = Q~ @ K~^T (wave owns P rows wv*16..+15) ----
  f32x4 pc[4];
#pragma unroll
  for (int n = 0; n < 4; n++) pc[n] = (f32x4){0.f, 0.f, 0.f, 0.f};
#pragma unroll
  for (int ks = 0; ks < 64; ks += 32) {
    bf16x8 aq = *(const bf16x8*)&Qs[(wv * 16 + m16) * 72 + ks + (ln >> 4) * 8];
#pragma unroll
    for (int n = 0; n < 4; ++n) {
      bf16x8 bk = *(const bf16x8*)&Ks[(n * 16 + m16) * 72 + ks + (ln >> 4) * 8];
      pc[n] = __builtin_amdgcn_mfma_f32_16x16x32_bf16(aq, bk, pc[n], 0, 0, 0);
    }
  }
  // causal mask (s<=t), round to bf16, store to own rows of Ps
#pragma unroll
  for (int n = 0; n < 4; ++n) {
    int s = n * 16 + cc;
#pragma unroll
    for (int r = 0; r < 4; ++r) {
      int t = wv * 16 + q4 + r;
      Ps[t * 72 + s] = f2bf(s <= t ? pc[n][r] : 0.f);
    }
  }

  // ---- MFMA3: S_chunk = K^hat^T @ V (independent of Ps) ----
  f32x4 sc[4];
#pragma unroll
  for (int n = 0; n < 4; n++) sc[n] = (f32x4){0.f, 0.f, 0.f, 0.f};
#pragma unroll
  for (int ks = 0; ks < 64; ks += 32) {
    bf16x8 ak = *(const bf16x8*)&Kht[(wv * 16 + m16) * 72 + ks + (ln >> 4) * 8];
#pragma unroll
    for (int n = 0; n < 4; ++n) {
      bf16x8 bv = *(const bf16x8*)&Vt[(n * 16 + m16) * 72 + ks + (ln >> 4) * 8];
      sc[n] = __builtin_amdgcn_mfma_f32_16x16x32_bf16(ak, bv, sc[n], 0, 0, 0);
    }
  }
  {
    float* sbp = SB + ((size_t)bh * 32 + ch) * 4096;
#pragma unroll
    for (int n = 0; n < 4; ++n)
#pragma unroll
      for (int r = 0; r < 4; ++r)
        sbp[(wv * 16 + q4 + r) * 64 + n * 16 + cc] = sc[n][r];
  }
  __syncthreads();  // Ps visible (belt-and-suspenders for same-wave DS RAW)

  // ---- MFMA2: O_intra = P @ V ----
  f32x4 oc[4];
#pragma unroll
  for (int n = 0; n < 4; n++) oc[n] = (f32x4){0.f, 0.f, 0.f, 0.f};
#pragma unroll
  for (int ks = 0; ks < 64; ks += 32) {
    bf16x8 ap = *(const bf16x8*)&Ps[(wv * 16 + m16) * 72 + ks + (ln >> 4) * 8];
#pragma unroll
    for (int n = 0; n < 4; ++n) {
      bf16x8 bv = *(const bf16x8*)&Vt[(n * 16 + m16) * 72 + ks + (ln >> 4) * 8];
      oc[n] = __builtin_amdgcn_mfma_f32_16x16x32_bf16(ap, bv, oc[n], 0, 0, 0);
    }
  }
#pragma unroll
  for (int n = 0; n < 4; ++n)
#pragma unroll
    for (int r = 0; r < 4; ++r)
      so[(wv * 16 + q4 + r) * 66 + n * 16 + cc] = f2bf(oc[n][r]);
  __syncthreads();
  // coalesced store of O_intra
#pragma unroll
  for (int j = 0; j < 4; ++j) {
    int row = (tid >> 4) + j * 16, cg = (tid & 15) * 4;
    unsigned a = *(const unsigned*)&so[row * 66 + cg];
    unsigned b = *(const unsigned*)&so[row * 66 + cg + 2];
    size_t g = base + (size_t)(row0 + row) * 1024 + cg;
    *(unsigned*)(ob + g) = a;
    *(unsigned*)(ob + g + 2) = b;
  }
}

// ---------------- Pass B: stitch chunk start states (in-place SB) ----------------
// 256 WGs = 64 bh x 4 k-quarters. Thread owns (k, 4 v). Entry: SB=S_loc; exit: SB=S_start.
__global__ __launch_bounds__(256, 2) void gla_stitch_c(float* __restrict__ SB,
                                                       const float* __restrict__ Dc) {
  const int bh = blockIdx.x >> 2, kq = blockIdx.x & 3;
  const int tid = threadIdx.x;
  const int kk = kq * 16 + (tid >> 4);
  const int v4 = (tid & 15) * 4;
  float4 s = {0.f, 0.f, 0.f, 0.f};
  const size_t sOff = ((size_t)bh * 32) * 4096 + (size_t)kk * 64 + v4;
  const size_t dOff = ((size_t)bh * 32) * 64 + kk;
  float4 l = *(float4*)(SB + sOff);
  float D = Dc[dOff];
  for (int chn = 0; chn < 32; ++chn) {
    float4 ln2 = {0.f, 0.f, 0.f, 0.f};
    float Dn = 0.f;
    if (chn + 1 < 32) {
      ln2 = *(float4*)(SB + sOff + (size_t)(chn + 1) * 4096);
      Dn = Dc[dOff + (size_t)(chn + 1) * 64];
    }
    *(float4*)(SB + sOff + (size_t)chn * 4096) = s;
    s.x = fmaf(D, s.x, l.x); s.y = fmaf(D, s.y, l.y);
    s.z = fmaf(D, s.z, l.z); s.w = fmaf(D, s.w, l.w);
    l = ln2; D = Dn;
  }
}

// ---------------- Pass C: o += q~ @ S_start, chunks 1..31 (fp32, verified) ----------------
__global__ __launch_bounds__(256, 4) void gla_corr(
    const USH* __restrict__ qtb, const float* __restrict__ SB, USH* __restrict__ ob) {
  const int bh = blockIdx.y, chn = blockIdx.x + 1;
  const size_t base = (size_t)(bh >> 4) * TSEQ * 1024 + (size_t)(bh & 15) * 64;
  const int trow0 = chn * 64;
  const int tid = threadIdx.x;
  __shared__ float ss[64 * 64];  // S_start[k][v] fp32
  __shared__ USH qs[64][72];
  const float* sp = SB + ((size_t)bh * 32 + chn) * 4096;
  for (int i = tid; i < 1024; i += 256)
    *((float4*)ss + i) = *((const float4*)sp + i);
#pragma unroll
  for (int j = 0; j < 4; ++j) {
    int i = tid + 256 * j;
    int row = i >> 4, cg = (i & 15) * 4;
    *(uint2*)&qs[row][cg] = *(const uint2*)(qtb + base + (size_t)(trow0 + row) * 1024 + cg);
  }
  __syncthreads();
  const int row = tid >> 2, vg = (tid & 3) * 16;
  float acc[16];
#pragma unroll
  for (int i = 0; i < 16; i++) acc[i] = 0.f;
  for (int k0 = 0; k0 < 64; k0 += 8) {
    uint4 qv = *(const uint4*)&qs[row][k0];
    float qf[8];
    qf[0] = bflo(qv.x); qf[1] = bfhi(qv.x);
    qf[2] = bflo(qv.y); qf[3] = bfhi(qv.y);
    qf[4] = bflo(qv.z); qf[5] = bfhi(qv.z);
    qf[6] = bflo(qv.w); qf[7] = bfhi(qv.w);
#pragma unroll
    for (int j = 0; j < 8; ++j) {
      const float* sr = &ss[(k0 + j) * 64 + vg];
      float4 s0 = *(const float4*)(sr + 0), s1 = *(const float4*)(sr + 4);
      float4 s2 = *(const float4*)(sr + 8), s3 = *(const float4*)(sr + 12);
      acc[0] = fmaf(qf[j], s0.x, acc[0]);   acc[1] = fmaf(qf[j], s0.y, acc[1]);
      acc[2] = fmaf(qf[j], s0.z, acc[2]);   acc[3] = fmaf(qf[j], s0.w, acc[3]);
      acc[4] = fmaf(qf[j], s1.x, acc[4]);   acc[5] = fmaf(qf[j], s1.y, acc[5]);
      acc[6] = fmaf(qf[j], s1.z, acc[6]);   acc[7] = fmaf(qf[j], s1.w, acc[7]);
      acc[8] = fmaf(qf[j], s2.x, acc[8]);   acc[9] = fmaf(qf[j], s2.y, acc[9]);
      acc[10] = fmaf(qf[j], s2.z, acc[10]); acc[11] = fmaf(qf[j], s2.w, acc[11]);
      acc[12] = fmaf(qf[j], s3.x, acc[12]); acc[13] = fmaf(qf[j], s3.y, acc[13]);
      acc[14] = fmaf(qf[j], s3.z, acc[14]); acc[15] = fmaf(qf[j], s3.w, acc[15]);
    }
  }
  USH* op = ob + base + (size_t)(trow0 + row) * 1024 + vg;
#pragma unroll
  for (int g = 0; g < 4; ++g) {
    ushort4 o4 = *(ushort4*)(op + g * 4);
    o4.x = f2bf(bflo((unsigned)o4.x) + acc[g * 4 + 0]);
    o4.y = f2bf(bflo((unsigned)o4.y) + acc[g * 4 + 1]);
    o4.z = f2bf(bflo((unsigned)o4.z) + acc[g * 4 + 2]);
    o4.w = f2bf(bflo((unsigned)o4.w) + acc[g * 4 + 3]);
    *(ushort4*)(op + g * 4) = o4;
  }
}

extern "C" void kernel_launch(void* const* d_in, const int* in_sizes, int n_in,
                              void* d_out, int out_size, void* d_ws, size_t ws_size,
                              hipStream_t stream) {
  const float* x  = (const float*)d_in[0];
  const float* Wq = (const float*)d_in[1];
  const float* Wk = (const float*)d_in[2];
  const float* Wv = (const float*)d_in[3];
  const float* Wg = (const float*)d_in[4];
  const float* bg = (const float*)d_in[5];
  const float* Wo = (const float*)d_in[6];
  float* out = (float*)d_out;

  // workspace layout (~114.5 MiB; SB's first 8 MiB doubles as WcatT — dead after GEMM1)
  char* ws = (char*)d_ws;
  size_t off = 0;
  auto alloc = [&](size_t bytes) {
    char* p = ws + off;
    off += (bytes + 255) & ~(size_t)255;
    return p;
  };
  USH* xb   = (USH*)alloc((size_t)MM * DM * 2);          // 16 MiB (reused as ob)
  USH* WoT  = (USH*)alloc((size_t)1024 * 1024 * 2);      // 2 MiB
  USH* qb   = (USH*)alloc((size_t)MM * DM * 2);          // 16 MiB
  USH* kb   = (USH*)alloc((size_t)MM * DM * 2);          // 16 MiB
  USH* vb   = (USH*)alloc((size_t)MM * DM * 2);          // 16 MiB
  USH* au   = (USH*)alloc((size_t)MM * DM * 2);          // 16 MiB u16 gate
  float* Dc = (float*)alloc((size_t)64 * 32 * 64 * 4);   // 512 KiB chunk decay
  float* SB = (float*)alloc((size_t)64 * 32 * 4096 * 4); // 32 MiB chunk states
  USH* WcatT = (USH*)SB;                                 // aliased (GEMM1 only)
  USH* ob = xb;                                          // xb dead after GEMM1

  cvt_x<<<(MM * DM) / 1024, 256, 0, stream>>>(x, xb);
  trans_cvt<<<dim3(32, 32, 5), dim3(32, 8), 0, stream>>>(Wq, Wk, Wv, Wg, Wo, WcatT, WoT);
  // fused QKV+gate GEMM: (8192x1024) x (1024x4096)
  gemm_bt<1><<<dim3(32, 64), 256, 0, stream>>>(xb, WcatT, 1024, qb, kb, vb, au, bg, nullptr);
  // Pass A: chunked MFMA scan (intra) + chunk summaries; writes q~ over qb
  gla_chunk<<<2048, 256, 0, stream>>>(qb, kb, vb, au, ob, SB, Dc);
  // Pass B: stitch chunk start states (in-place in SB)
  gla_stitch_c<<<256, 256, 0, stream>>>(SB, Dc);
  // Pass C: cross-chunk correction (fp32 S)
  gla_corr<<<dim3(31, 64), 256, 0, stream>>>(qb, SB, ob);
  // output projection: (8192x1024) x (1024x1024) -> f32 d_out
  gemm_bt<0><<<dim3(8, 64), 256, 0, stream>>>(ob, WoT, 1024, nullptr, nullptr, nullptr,
                                              nullptr, nullptr, out);
}

// Round 5
// 271.786 us; speedup vs baseline: 2.6302x; 1.0870x over previous
//
#include <hip/hip_runtime.h>
#include <hip/hip_bf16.h>

// Problem constants (GLA layer): D_MODEL=1024, D_K=D_V=64, H=16, B=4, T=2048
#define DM   1024
#define NH   16
#define TSEQ 2048
#define BBATCH 4
#define MM   (BBATCH*TSEQ)   // 8192 rows of x

typedef unsigned short USH;
typedef __attribute__((ext_vector_type(8))) short bf16x8;
typedef __attribute__((ext_vector_type(4))) float f32x4;

__device__ __forceinline__ USH f2bf(float f) {
  __hip_bfloat16 h = __float2bfloat16(f);
  return __builtin_bit_cast(USH, h);
}
__device__ __forceinline__ float bflo(unsigned u) { return __uint_as_float(u << 16); }
__device__ __forceinline__ float bfhi(unsigned u) { return __uint_as_float(u & 0xffff0000u); }

// async global->LDS, 16B per lane. LDS dst = wave-uniform base + lane*16.
__device__ __forceinline__ void load16_lds(const void* g, void* l) {
  __builtin_amdgcn_global_load_lds(
      (const __attribute__((address_space(1))) unsigned int*)g,
      (__attribute__((address_space(3))) unsigned int*)l, 16, 0, 0);
}

// ---------------- elementwise f32 -> bf16 (x) ----------------
__global__ void cvt_x(const float* __restrict__ x, USH* __restrict__ xb) {
  int i = (blockIdx.x * blockDim.x + threadIdx.x) * 4;
  float4 f = *(const float4*)(x + i);
  ushort4 u;
  u.x = f2bf(f.x); u.y = f2bf(f.y); u.z = f2bf(f.z); u.w = f2bf(f.w);
  *(ushort4*)(xb + i) = u;
}

// ------------- transpose+convert 1024x1024 f32 -> bf16 (B^T layout) -------------
__global__ void trans_cvt(const float* __restrict__ w0, const float* __restrict__ w1,
                          const float* __restrict__ w2, const float* __restrict__ w3,
                          const float* __restrict__ w4,
                          USH* __restrict__ wcatT, USH* __restrict__ woT) {
  int z = blockIdx.z;
  const float* src = (z == 0) ? w0 : (z == 1) ? w1 : (z == 2) ? w2 : (z == 3) ? w3 : w4;
  USH* dst = (z < 4) ? (wcatT + (size_t)z * 1024 * 1024) : woT;
  __shared__ float tile[32][33];
  int x = blockIdx.x * 32 + threadIdx.x;
  int y = blockIdx.y * 32;
  for (int j = threadIdx.y; j < 32; j += 8)
    tile[j][threadIdx.x] = src[(size_t)(y + j) * 1024 + x];
  __syncthreads();
  int x2 = blockIdx.y * 32 + threadIdx.x;
  int y2 = blockIdx.x * 32;
  for (int j = threadIdx.y; j < 32; j += 8)
    dst[(size_t)(y2 + j) * 1024 + x2] = f2bf(tile[threadIdx.x][j]);
}

// ---------------- MFMA GEMM: C(MxN) = A(MxK) * B^T(NxK), bf16 in, f32 acc ----------------
// LDS layout is XOR-swizzled: physical 16B-chunk p of row r holds global k-chunk p^(r&7).
// Swizzle applied on the GLOBAL address at staging (global_load_lds dst must stay
// lane-linear) and undone at ds_read -> each 16-lane fragment read spreads across
// all 32 banks (2-way = free) instead of 16-way on a 4-bank group.
// EPI=1: N=4096 fused QKVG epilogue (block-uniform target: bn>>3): q/k/v bf16,
//        gate -> sigmoid as u16 fixed-point. Staged through LDS for dwordx4 stores.
// EPI=0: f32 out, staged through LDS in two 64-row halves (row stride 132 floats —
//        128 data cols + 4 pad; stride-68 in R4 aliased rows and corrupted output).
template <int EPI>
__global__ __launch_bounds__(256, 2) void gemm_bt(
    const USH* __restrict__ A, const USH* __restrict__ B, int K,
    USH* __restrict__ q_out, USH* __restrict__ k_out, USH* __restrict__ v_out,
    USH* __restrict__ a_out, const float* __restrict__ bias,
    float* __restrict__ c_out) {
  __shared__ __align__(16) char smem[34816];  // 32 KB loop (As+Bs), 34 KB epilogue
  short* As = (short*)smem;
  short* Bs = (short*)(smem + 16384);
  const int tid = threadIdx.x;
  const int wave = tid >> 6;
  const int lane = tid & 63;
  const int bm = blockIdx.y, bn = blockIdx.x;
  const int wm = (wave >> 1) * 64;
  const int wn = (wave & 1) * 64;

  f32x4 acc[4][4];
#pragma unroll
  for (int i = 0; i < 4; i++)
#pragma unroll
    for (int j = 0; j < 4; j++) acc[i][j] = (f32x4){0.f, 0.f, 0.f, 0.f};

  const int srow = wave * 8 + (lane >> 3);              // row within 32-row staging group
  const int scol = ((lane & 7) ^ (lane >> 3)) * 8;      // swizzled global k-offset

  for (int k0 = 0; k0 < K; k0 += 64) {
#pragma unroll
    for (int i = 0; i < 4; ++i) {
      int row = i * 32 + srow;
      const USH* ga = A + (size_t)(bm * 128 + row) * K + k0 + scol;
      const USH* gb = B + (size_t)(bn * 128 + row) * K + k0 + scol;
      int lofs = __builtin_amdgcn_readfirstlane((i * 32 + wave * 8) * 64);
      load16_lds(ga, (void*)(As + lofs));
      load16_lds(gb, (void*)(Bs + lofs));
    }
    __syncthreads();
    const int m16 = lane & 15;
    const int sw = lane & 7;          // = row&7 for all fragment rows
    const int kc = lane >> 4;         // fragment k-chunk within 32-k step
#pragma unroll
    for (int ks = 0; ks < 64; ks += 32) {
      bf16x8 af[4], bf[4];
#pragma unroll
      for (int i = 0; i < 4; i++)
        af[i] = *(const bf16x8*)&As[(wm + i * 16 + m16) * 64 + ((((ks >> 3) + kc) ^ sw) << 3)];
#pragma unroll
      for (int j = 0; j < 4; j++)
        bf[j] = *(const bf16x8*)&Bs[(wn + j * 16 + m16) * 64 + ((((ks >> 3) + kc) ^ sw) << 3)];
#pragma unroll
      for (int i = 0; i < 4; i++)
#pragma unroll
        for (int j = 0; j < 4; j++)
          acc[i][j] = __builtin_amdgcn_mfma_f32_16x16x32_bf16(af[i], bf[j], acc[i][j], 0, 0, 0);
    }
    __syncthreads();
  }

  // epilogue. C/D layout: col = lane&15, row = (lane>>4)*4 + reg  [m89-verified]
  const int r0 = (lane >> 4) * 4;
  const int cc = lane & 15;
  if (EPI == 1) {
    USH* ep = (USH*)smem;  // [128][136]; row pitch 272B: 16B-aligned, 4-bank row shift
    const int which = bn >> 3;  // block-uniform output select
    float bj[4];
    if (which == 3) {
#pragma unroll
      for (int j = 0; j < 4; j++) bj[j] = bias[(bn & 7) * 128 + wn + j * 16 + cc];
    }
#pragma unroll
    for (int i = 0; i < 4; i++)
#pragma unroll
      for (int j = 0; j < 4; j++)
#pragma unroll
        for (int r = 0; r < 4; r++) {
          float val = acc[i][j][r];
          USH o;
          if (which == 3) {
            float s = 1.0f / (1.0f + __expf(-(val + bj[j])));
            o = (USH)(s * 65535.0f + 0.5f);  // u16 gate: rel err ~8e-6
          } else {
            o = f2bf(val);
          }
          ep[(wm + i * 16 + r0 + r) * 136 + wn + j * 16 + cc] = o;
        }
    __syncthreads();
    USH* dst = (which == 0) ? q_out : (which == 1) ? k_out : (which == 2) ? v_out : a_out;
    const int rr = tid >> 4, ccol = (tid & 15) * 8;
#pragma unroll
    for (int it = 0; it < 8; ++it) {
      int row = it * 16 + rr;
      uint4 vd = *(const uint4*)&ep[row * 136 + ccol];
      *(uint4*)(dst + (size_t)(bm * 128 + row) * 1024 + (bn & 7) * 128 + ccol) = vd;
    }
  } else {
    float* epf = (float*)smem;  // [64][132] f32 (128 cols + 4 pad), two 64-row halves
#pragma unroll
    for (int h = 0; h < 2; ++h) {
      if (wm == h * 64) {
#pragma unroll
        for (int i = 0; i < 4; i++)
#pragma unroll
          for (int j = 0; j < 4; j++)
#pragma unroll
            for (int r = 0; r < 4; r++)
              epf[(i * 16 + r0 + r) * 132 + wn + j * 16 + cc] = acc[i][j][r];
      }
      __syncthreads();
      const int rr = tid >> 5, c4 = (tid & 31) * 4;
#pragma unroll
      for (int it = 0; it < 8; ++it) {
        int row = it * 8 + rr;
        float4 vd = *(const float4*)&epf[row * 132 + c4];
        *(float4*)(c_out + (size_t)(bm * 128 + h * 64 + row) * 1024 + bn * 128 + c4) = vd;
      }
      if (h == 0) __syncthreads();
    }
  }
}

// ---------------- Pass A: per-chunk MFMA scan (C=64) ----------------
// Grid 2048 = 64 bh x 32 chunks, 256 threads (4 waves).
// P = (Q*A) @ (K/A)^T masked causal; O_intra = P@V; S_chunk = Khat^T@V; Dc = A[63].
// Writes q~ in-place to qb (bf16) for pass C.
__global__ __launch_bounds__(256, 3) void gla_chunk(
    USH* __restrict__ qb, const USH* __restrict__ kb, const USH* __restrict__ vb,
    const USH* __restrict__ au, USH* __restrict__ ob,
    float* __restrict__ SB, float* __restrict__ Dc) {
  const int bh = blockIdx.x >> 5, ch = blockIdx.x & 31;
  const size_t base = (size_t)(bh >> 4) * TSEQ * 1024 + (size_t)(bh & 15) * 64;
  const int row0 = ch * 64;
  const int tid = threadIdx.x, wv = tid >> 6, ln = tid & 63;

  __shared__ __align__(16) char smem[54528];
  USH* Qs  = (USH*)smem;             // [64][72] bf16 q~
  USH* Ks  = (USH*)(smem + 9216);    // [64][72] bf16 k~ (rows s)
  USH* Kht = (USH*)(smem + 18432);   // [64][72] bf16 k^ transposed (rows k)
  USH* Vt  = (USH*)(smem + 27648);   // [64][72] bf16 V transposed (rows v)
  float* psum = (float*)(smem + 27648);  // aliases Vt head; dead before Vt written
  USH* Ps  = (USH*)(smem + 36864);   // [64][72] masked P, bf16 (aliases Ag)
  USH* so  = (USH*)(smem + 46080);   // [64][66] O_intra bf16 (aliases Ag tail)
  float* Ag = (float*)(smem + 36864); // [64][65] fp32 cumprod; dead before Ps/so

  // ---- phase 1: per-column cumulative product of gates (fp32) ----
  {
    const int c1 = tid & 63, sg = tid >> 6;
    float lp[16], p = 1.f;
#pragma unroll
    for (int r = 0; r < 16; ++r) {
      float a = (float)au[base + (size_t)(row0 + sg * 16 + r) * 1024 + c1] * (1.f / 65535.f);
      p *= a;
      lp[r] = p;
    }
    psum[sg * 64 + c1] = p;
    __syncthreads();
    float pre = 1.f;
    for (int s2 = 0; s2 < sg; ++s2) pre *= psum[s2 * 64 + c1];
#pragma unroll
    for (int r = 0; r < 16; ++r) Ag[(sg * 16 + r) * 65 + c1] = pre * lp[r];
  }
  __syncthreads();
  if (tid < 64) Dc[((size_t)bh * 32 + ch) * 64 + tid] = Ag[63 * 65 + tid];

  // ---- phase 2: build q~, k~, k^T, V^T in LDS; write q~ back to qb ----
  {
    const int rr = tid >> 4, cg = (tid & 15) * 4;
    float AC[4];
#pragma unroll
    for (int i = 0; i < 4; i++) AC[i] = Ag[63 * 65 + cg + i];
#pragma unroll
    for (int j = 0; j < 4; ++j) {
      int row = rr + j * 16;
      size_t g = base + (size_t)(row0 + row) * 1024 + cg;
      uint2 qv = *(const uint2*)(qb + g);
      uint2 kv = *(const uint2*)(kb + g);
      uint2 vv = *(const uint2*)(vb + g);
      float A0 = Ag[row * 65 + cg], A1 = Ag[row * 65 + cg + 1];
      float A2 = Ag[row * 65 + cg + 2], A3 = Ag[row * 65 + cg + 3];
      ushort4 qt;
      qt.x = f2bf(bflo(qv.x) * A0); qt.y = f2bf(bfhi(qv.x) * A1);
      qt.z = f2bf(bflo(qv.y) * A2); qt.w = f2bf(bfhi(qv.y) * A3);
      *(ushort4*)&Qs[row * 72 + cg] = qt;
      *(ushort4*)(qb + g) = qt;  // for pass C
      float R0 = 1.f / A0, R1 = 1.f / A1, R2 = 1.f / A2, R3 = 1.f / A3;
      float kt0 = bflo(kv.x) * R0, kt1 = bfhi(kv.x) * R1;
      float kt2 = bflo(kv.y) * R2, kt3 = bfhi(kv.y) * R3;
      ushort4 kt;
      kt.x = f2bf(kt0); kt.y = f2bf(kt1); kt.z = f2bf(kt2); kt.w = f2bf(kt3);
      *(ushort4*)&Ks[row * 72 + cg] = kt;
      Kht[(cg + 0) * 72 + row] = f2bf(kt0 * AC[0]);
      Kht[(cg + 1) * 72 + row] = f2bf(kt1 * AC[1]);
      Kht[(cg + 2) * 72 + row] = f2bf(kt2 * AC[2]);
      Kht[(cg + 3) * 72 + row] = f2bf(kt3 * AC[3]);
      Vt[(cg + 0) * 72 + row] = (USH)(vv.x & 0xffff);
      Vt[(cg + 1) * 72 + row] = (USH)(vv.x >> 16);
      Vt[(cg + 2) * 72 + row] = (USH)(vv.y & 0xffff);
      Vt[(cg + 3) * 72 + row] = (USH)(vv.y >> 16);
    }
  }
  __syncthreads();

  const int q4 = (ln >> 4) * 4, cc = ln & 15, m16 = ln & 15;

  // ---- MFMA1: P = Q~ @ K~^T (wave owns P rows wv*16..+15) ----
  f32x4 pc[4];
#pragma unroll
  for (int n = 0; n < 4; n++) pc[n] = (f32x4){0.f, 0.f, 0.f, 0.f};
#pragma unroll
  for (int ks = 0; ks < 64; ks += 32) {
    bf16x8 aq = *(const bf16x8*)&Qs[(wv * 16 + m16) * 72 + ks + (ln >> 4) * 8];
#pragma unroll
    for (int n = 0; n < 4; ++n) {
      bf16x8 bk = *(const bf16x8*)&Ks[(n * 16 + m16) * 72 + ks + (ln >> 4) * 8];
      pc[n] = __builtin_amdgcn_mfma_f32_16x16x32_bf16(aq, bk, pc[n], 0, 0, 0);
    }
  }
  // causal mask (s<=t), round to bf16, store to own rows of Ps
#pragma unroll
  for (int n = 0; n < 4; ++n) {
    int s = n * 16 + cc;
#pragma unroll
    for (int r = 0; r < 4; ++r) {
      int t = wv * 16 + q4 + r;
      Ps[t * 72 + s] = f2bf(s <= t ? pc[n][r] : 0.f);
    }
  }

  // ---- MFMA3: S_chunk = K^hat^T @ V (independent of Ps) ----
  f32x4 sc[4];
#pragma unroll
  for (int n = 0; n < 4; n++) sc[n] = (f32x4){0.f, 0.f, 0.f, 0.f};
#pragma unroll
  for (int ks = 0; ks < 64; ks += 32) {
    bf16x8 ak = *(const bf16x8*)&Kht[(wv * 16 + m16) * 72 + ks + (ln >> 4) * 8];
#pragma unroll
    for (int n = 0; n < 4; ++n) {
      bf16x8 bv = *(const bf16x8*)&Vt[(n * 16 + m16) * 72 + ks + (ln >> 4) * 8];
      sc[n] = __builtin_amdgcn_mfma_f32_16x16x32_bf16(ak, bv, sc[n], 0, 0, 0);
    }
  }
  {
    float* sbp = SB + ((size_t)bh * 32 + ch) * 4096;
#pragma unroll
    for (int n = 0; n < 4; ++n)
#pragma unroll
      for (int r = 0; r < 4; ++r)
        sbp[(wv * 16 + q4 + r) * 64 + n * 16 + cc] = sc[n][r];
  }
  __syncthreads();  // Ps visible

  // ---- MFMA2: O_intra = P @ V ----
  f32x4 oc[4];
#pragma unroll
  for (int n = 0; n < 4; n++) oc[n] = (f32x4){0.f, 0.f, 0.f, 0.f};
#pragma unroll
  for (int ks = 0; ks < 64; ks += 32) {
    bf16x8 ap = *(const bf16x8*)&Ps[(wv * 16 + m16) * 72 + ks + (ln >> 4) * 8];
#pragma unroll
    for (int n = 0; n < 4; ++n) {
      bf16x8 bv = *(const bf16x8*)&Vt[(n * 16 + m16) * 72 + ks + (ln >> 4) * 8];
      oc[n] = __builtin_amdgcn_mfma_f32_16x16x32_bf16(ap, bv, oc[n], 0, 0, 0);
    }
  }
#pragma unroll
  for (int n = 0; n < 4; ++n)
#pragma unroll
    for (int r = 0; r < 4; ++r)
      so[(wv * 16 + q4 + r) * 66 + n * 16 + cc] = f2bf(oc[n][r]);
  __syncthreads();
  // coalesced store of O_intra
#pragma unroll
  for (int j = 0; j < 4; ++j) {
    int row = (tid >> 4) + j * 16, cg = (tid & 15) * 4;
    unsigned a = *(const unsigned*)&so[row * 66 + cg];
    unsigned b = *(const unsigned*)&so[row * 66 + cg + 2];
    size_t g = base + (size_t)(row0 + row) * 1024 + cg;
    *(unsigned*)(ob + g) = a;
    *(unsigned*)(ob + g + 2) = b;
  }
}

// ---------------- Pass B: stitch chunk start states (in-place SB) ----------------
__global__ __launch_bounds__(256, 2) void gla_stitch_c(float* __restrict__ SB,
                                                       const float* __restrict__ Dc) {
  const int bh = blockIdx.x >> 2, kq = blockIdx.x & 3;
  const int tid = threadIdx.x;
  const int kk = kq * 16 + (tid >> 4);
  const int v4 = (tid & 15) * 4;
  float4 s = {0.f, 0.f, 0.f, 0.f};
  const size_t sOff = ((size_t)bh * 32) * 4096 + (size_t)kk * 64 + v4;
  const size_t dOff = ((size_t)bh * 32) * 64 + kk;
  float4 l = *(float4*)(SB + sOff);
  float D = Dc[dOff];
  for (int chn = 0; chn < 32; ++chn) {
    float4 ln2 = {0.f, 0.f, 0.f, 0.f};
    float Dn = 0.f;
    if (chn + 1 < 32) {
      ln2 = *(float4*)(SB + sOff + (size_t)(chn + 1) * 4096);
      Dn = Dc[dOff + (size_t)(chn + 1) * 64];
    }
    *(float4*)(SB + sOff + (size_t)chn * 4096) = s;
    s.x = fmaf(D, s.x, l.x); s.y = fmaf(D, s.y, l.y);
    s.z = fmaf(D, s.z, l.z); s.w = fmaf(D, s.w, l.w);
    l = ln2; D = Dn;
  }
}

// ---------------- Pass C: o += q~ @ S_start, chunks 1..31 (fp32) ----------------
__global__ __launch_bounds__(256, 4) void gla_corr(
    const USH* __restrict__ qtb, const float* __restrict__ SB, USH* __restrict__ ob) {
  const int bh = blockIdx.y, chn = blockIdx.x + 1;
  const size_t base = (size_t)(bh >> 4) * TSEQ * 1024 + (size_t)(bh & 15) * 64;
  const int trow0 = chn * 64;
  const int tid = threadIdx.x;
  __shared__ float ss[64 * 64];  // S_start[k][v] fp32
  __shared__ USH qs[64][72];
  const float* sp = SB + ((size_t)bh * 32 + chn) * 4096;
  for (int i = tid; i < 1024; i += 256)
    *((float4*)ss + i) = *((const float4*)sp + i);
#pragma unroll
  for (int j = 0; j < 4; ++j) {
    int i = tid + 256 * j;
    int row = i >> 4, cg = (i & 15) * 4;
    *(uint2*)&qs[row][cg] = *(const uint2*)(qtb + base + (size_t)(trow0 + row) * 1024 + cg);
  }
  __syncthreads();
  const int row = tid >> 2, vg = (tid & 3) * 16;
  float acc[16];
#pragma unroll
  for (int i = 0; i < 16; i++) acc[i] = 0.f;
  for (int k0 = 0; k0 < 64; k0 += 8) {
    uint4 qv = *(const uint4*)&qs[row][k0];
    float qf[8];
    qf[0] = bflo(qv.x); qf[1] = bfhi(qv.x);
    qf[2] = bflo(qv.y); qf[3] = bfhi(qv.y);
    qf[4] = bflo(qv.z); qf[5] = bfhi(qv.z);
    qf[6] = bflo(qv.w); qf[7] = bfhi(qv.w);
#pragma unroll
    for (int j = 0; j < 8; ++j) {
      const float* sr = &ss[(k0 + j) * 64 + vg];
      float4 s0 = *(const float4*)(sr + 0), s1 = *(const float4*)(sr + 4);
      float4 s2 = *(const float4*)(sr + 8), s3 = *(const float4*)(sr + 12);
      acc[0] = fmaf(qf[j], s0.x, acc[0]);   acc[1] = fmaf(qf[j], s0.y, acc[1]);
      acc[2] = fmaf(qf[j], s0.z, acc[2]);   acc[3] = fmaf(qf[j], s0.w, acc[3]);
      acc[4] = fmaf(qf[j], s1.x, acc[4]);   acc[5] = fmaf(qf[j], s1.y, acc[5]);
      acc[6] = fmaf(qf[j], s1.z, acc[6]);   acc[7] = fmaf(qf[j], s1.w, acc[7]);
      acc[8] = fmaf(qf[j], s2.x, acc[8]);   acc[9] = fmaf(qf[j], s2.y, acc[9]);
      acc[10] = fmaf(qf[j], s2.z, acc[10]); acc[11] = fmaf(qf[j], s2.w, acc[11]);
      acc[12] = fmaf(qf[j], s3.x, acc[12]); acc[13] = fmaf(qf[j], s3.y, acc[13]);
      acc[14] = fmaf(qf[j], s3.z, acc[14]); acc[15] = fmaf(qf[j], s3.w, acc[15]);
    }
  }
  USH* op = ob + base + (size_t)(trow0 + row) * 1024 + vg;
#pragma unroll
  for (int g = 0; g < 4; ++g) {
    ushort4 o4 = *(ushort4*)(op + g * 4);
    o4.x = f2bf(bflo((unsigned)o4.x) + acc[g * 4 + 0]);
    o4.y = f2bf(bflo((unsigned)o4.y) + acc[g * 4 + 1]);
    o4.z = f2bf(bflo((unsigned)o4.z) + acc[g * 4 + 2]);
    o4.w = f2bf(bflo((unsigned)o4.w) + acc[g * 4 + 3]);
    *(ushort4*)(op + g * 4) = o4;
  }
}

extern "C" void kernel_launch(void* const* d_in, const int* in_sizes, int n_in,
                              void* d_out, int out_size, void* d_ws, size_t ws_size,
                              hipStream_t stream) {
  const float* x  = (const float*)d_in[0];
  const float* Wq = (const float*)d_in[1];
  const float* Wk = (const float*)d_in[2];
  const float* Wv = (const float*)d_in[3];
  const float* Wg = (const float*)d_in[4];
  const float* bg = (const float*)d_in[5];
  const float* Wo = (const float*)d_in[6];
  float* out = (float*)d_out;

  // workspace layout (~114.5 MiB; SB's first 8 MiB doubles as WcatT — dead after GEMM1)
  char* ws = (char*)d_ws;
  size_t off = 0;
  auto alloc = [&](size_t bytes) {
    char* p = ws + off;
    off += (bytes + 255) & ~(size_t)255;
    return p;
  };
  USH* xb   = (USH*)alloc((size_t)MM * DM * 2);          // 16 MiB (reused as ob)
  USH* WoT  = (USH*)alloc((size_t)1024 * 1024 * 2);      // 2 MiB
  USH* qb   = (USH*)alloc((size_t)MM * DM * 2);          // 16 MiB
  USH* kb   = (USH*)alloc((size_t)MM * DM * 2);          // 16 MiB
  USH* vb   = (USH*)alloc((size_t)MM * DM * 2);          // 16 MiB
  USH* au   = (USH*)alloc((size_t)MM * DM * 2);          // 16 MiB u16 gate
  float* Dc = (float*)alloc((size_t)64 * 32 * 64 * 4);   // 512 KiB chunk decay
  float* SB = (float*)alloc((size_t)64 * 32 * 4096 * 4); // 32 MiB chunk states
  USH* WcatT = (USH*)SB;                                 // aliased (GEMM1 only)
  USH* ob = xb;                                          // xb dead after GEMM1

  cvt_x<<<(MM * DM) / 1024, 256, 0, stream>>>(x, xb);
  trans_cvt<<<dim3(32, 32, 5), dim3(32, 8), 0, stream>>>(Wq, Wk, Wv, Wg, Wo, WcatT, WoT);
  // fused QKV+gate GEMM: (8192x1024) x (1024x4096)
  gemm_bt<1><<<dim3(32, 64), 256, 0, stream>>>(xb, WcatT, 1024, qb, kb, vb, au, bg, nullptr);
  // Pass A: chunked MFMA scan (intra) + chunk summaries; writes q~ over qb
  gla_chunk<<<2048, 256, 0, stream>>>(qb, kb, vb, au, ob, SB, Dc);
  // Pass B: stitch chunk start states (in-place in SB)
  gla_stitch_c<<<256, 256, 0, stream>>>(SB, Dc);
  // Pass C: cross-chunk correction (fp32 S)
  gla_corr<<<dim3(31, 64), 256, 0, stream>>>(qb, SB, ob);
  // output projection: (8192x1024) x (1024x1024) -> f32 d_out
  gemm_bt<0><<<dim3(8, 64), 256, 0, stream>>>(ob, WoT, 1024, nullptr, nullptr, nullptr,
                                              nullptr, nullptr, out);
}